// Round 6
// baseline (760.549 us; speedup 1.0000x reference)
//
#include <hip/hip_runtime.h>

// WaveNet residual stack, MFMA bf16. Per stack: 1 fused kernel (d=1..32, halo
// tiles in LDS) + 4 single-block kernels (d=64..512) => 20 chain launches.
// Swapped-operand MFMA (reg->channel, lane->time) so all LDS accumulator
// traffic is packed b64/b128. Skip GEMMs ride as balanced piggyback WGs
// (capacity 3 blocks/launch) + small tail. Stream fp32; operands bf16.

#define CC    64
#define SCC   256
#define BB    4
#define LL0   8192
#define NBLK  40
#define SKIPN 4096
#define TTC   32

typedef __attribute__((ext_vector_type(8))) short bf16x8;
typedef __attribute__((ext_vector_type(4))) float f32x4;
typedef unsigned short us;

__device__ __forceinline__ us f2bf(float f) {
    union { float f; unsigned u; } v; v.f = f;
    return (us)((v.u + 0x7FFF + ((v.u >> 16) & 1)) >> 16);
}
__device__ __forceinline__ unsigned pk2(float a, float b) {
    return (unsigned)f2bf(a) | ((unsigned)f2bf(b) << 16);
}
__device__ __forceinline__ uint2 pk4(f32x4 v) {
    return (uint2){pk2(v[0], v[1]), pk2(v[2], v[3])};
}
__device__ __forceinline__ bf16x8 pack8(f32x4 u0, f32x4 u1) {
    bf16x8 r;
    r[0]=(short)f2bf(u0[0]); r[1]=(short)f2bf(u0[1]);
    r[2]=(short)f2bf(u0[2]); r[3]=(short)f2bf(u0[3]);
    r[4]=(short)f2bf(u1[0]); r[5]=(short)f2bf(u1[1]);
    r[6]=(short)f2bf(u1[2]); r[7]=(short)f2bf(u1[3]);
    return r;
}
// fp32 [row][64] LDS word index, 32B-chunk XOR swizzle
__device__ __forceinline__ int sws(int r, int c) {
    return (r << 6) + ((((c >> 3) ^ r) & 7) << 3) + (c & 7);
}
// bf16 [row][64] LDS elem index, 16B-chunk XOR swizzle
__device__ __forceinline__ int swh(int r, int c) {
    return (r << 6) + ((((c >> 3) ^ r) & 7) << 3) + (c & 7);
}
// bf16 [row][128] LDS elem index, XOR on low 3 chunk bits
__device__ __forceinline__ int swx(int r, int k) {
    int ch = k >> 3; ch = (ch & 8) | ((ch ^ r) & 7);
    return (r << 7) + (ch << 3) + (k & 7);
}

// ---- merged prep: x transpose [b][c][t]->[b][t][c] + weight bf16 casts ----
__global__ __launch_bounds__(256) void prep_kernel(
    const float* __restrict__ x, float* __restrict__ xt_out,
    const float* __restrict__ dc_w, const float* __restrict__ conv_w,
    const float* __restrict__ skip_w,
    us* __restrict__ wcat, us* __restrict__ cwb, us* __restrict__ swb)
{
    if (blockIdx.x < 512) {
        __shared__ float tile[64][65];
        const int b = blockIdx.x >> 7, t0 = (blockIdx.x & 127) * 64;
        const int tid = threadIdx.x;
        #pragma unroll
        for (int p = 0; p < 4; ++p) {
            const int c = p * 16 + (tid >> 4), j = tid & 15;
            const float4 v = *(const float4*)(x + ((size_t)b * CC + c) * LL0 + t0 + j * 4);
            tile[c][j*4+0]=v.x; tile[c][j*4+1]=v.y; tile[c][j*4+2]=v.z; tile[c][j*4+3]=v.w;
        }
        __syncthreads();
        #pragma unroll
        for (int p = 0; p < 4; ++p) {
            const int r = p * 16 + (tid >> 4), h = tid & 15;
            float4 v = {tile[h*4+0][r], tile[h*4+1][r], tile[h*4+2][r], tile[h*4+3][r]};
            *(float4*)(xt_out + ((size_t)b * LL0 + t0 + r) * CC + h * 4) = v;
        }
        return;
    }
    const int n_sw = NBLK * SCC * CC, n_cw = NBLK * CC * CC, n_wc = NBLK * CC * 128;
    for (int idx = (blockIdx.x - 512) * blockDim.x + threadIdx.x; idx < n_sw;
         idx += 1024 * blockDim.x) {
        swb[idx] = f2bf(skip_w[idx]);
        if (idx < n_cw) cwb[idx] = f2bf(conv_w[idx]);
        if (idx < n_wc) {
            const int i = idx >> 13, o = (idx >> 7) & 63, kk = idx & 127;
            wcat[idx] = f2bf(dc_w[(((i * CC + o) * CC) + (kk & 63)) * 2 + (kk >> 6)]);
        }
    }
}

// ---- skip GEMM body; NW waves/WG, tile = NW*16 time rows ----
template<int NW>
__device__ __forceinline__ void skip_body(
    int e, int blk0,
    const us* __restrict__ g_all, const us* __restrict__ swb,
    const float* __restrict__ skip_b, float* __restrict__ out)
{
    constexpr int ROWS = NW * 16;
    constexpr int TPB = (SKIPN / ROWS) * BB;
    const int tid = threadIdx.x, lane = tid & 63, wv = tid >> 6;
    const int j = blk0 + e / TPB;
    const int id = e % TPB;
    const int tt = id % (SKIPN / ROWS);
    const int b  = id / (SKIPN / ROWS);
    const us* g  = g_all + ((size_t)j * BB + b) * SKIPN * CC;
    const us* sw = swb + (size_t)j * SCC * CC;
    const float* sb = skip_b + j * SCC;
    float* op = out + ((size_t)j * BB + b) * SCC * SKIPN;

    const int trow = tt * ROWS + wv * 16 + (lane & 15);
    bf16x8 a[2];
    a[0] = *(const bf16x8*)(g + (size_t)trow * CC + (lane >> 4) * 8);
    a[1] = *(const bf16x8*)(g + (size_t)trow * CC + 32 + (lane >> 4) * 8);
    const int tstore = tt * ROWS + wv * 16 + ((lane >> 4) << 2);
    #pragma unroll 4
    for (int n = 0; n < 16; ++n) {
        const int sc = n * 16 + (lane & 15);
        const float bias = sb[sc];
        f32x4 acc = (f32x4){bias, bias, bias, bias};
        const us* wrow = sw + sc * CC + (lane >> 4) * 8;
        acc = __builtin_amdgcn_mfma_f32_16x16x32_bf16(a[0], *(const bf16x8*)(wrow), acc, 0, 0, 0);
        acc = __builtin_amdgcn_mfma_f32_16x16x32_bf16(a[1], *(const bf16x8*)(wrow + 32), acc, 0, 0, 0);
        *(float4*)(op + (size_t)sc * SKIPN + tstore) = (float4){acc[0], acc[1], acc[2], acc[3]};
    }
}

// ---- fused multi-block kernel (512 threads); d = DB<<j ----
template<int NB, int DB, int TOUT, int RCAP, int MAXCH>
__global__ __launch_bounds__(512) void fused_kernel(
    const float* __restrict__ cur, float* __restrict__ nxt,
    const us* __restrict__ wcat_all, const us* __restrict__ cwb_all,
    const float* __restrict__ db_all, const float* __restrict__ cb_all,
    us* __restrict__ g_all, int blk0, int Lin, int ntiles,
    const us* __restrict__ swb, const float* __restrict__ skip_b,
    float* __restrict__ out, int pb0)
{
    const int wg = blockIdx.x, chain = BB * ntiles;
    if (wg >= chain) { skip_body<8>(wg - chain, pb0, g_all, swb, skip_b, out); return; }

    constexpr int H  = DB * ((1 << NB) - 1);
    constexpr int R0 = TOUT + H;
    __shared__ __align__(16) float sm[RCAP * CC];    // fp32 stream
    __shared__ __align__(16) us  gsm[RCAP * CC];     // relu(h) bf16

    const int tid = threadIdx.x, lane = tid & 63, wv = tid >> 6;
    const int b = wg / ntiles, t0 = (wg % ntiles) * TOUT;
    const float* src = cur + (size_t)b * LL0 * CC;

    // stage R0 stream rows (coalesced 256B rows)
    for (int base = 0; base < R0; base += 32) {
        const int row = base + (tid >> 4);
        const int h4 = (tid & 15) * 4;
        if (row < R0) {
            int gt = t0 + row; if (gt > Lin - 1) gt = Lin - 1;
            *(f32x4*)(sm + sws(row, h4)) = *(const f32x4*)(src + (size_t)gt * CC + h4);
        }
    }
    __syncthreads();

    const int rf = wv >> 1, oh = wv & 1;
    const int c8 = (lane >> 4) * 8;
    int Rcur = R0, Lj = Lin;

    for (int j = 0; j < NB; ++j) {
        const int d = DB << j;
        const int Rn = Rcur - d;
        Lj -= d;
        const us* wj = wcat_all + (size_t)(blk0 + j) * CC * 128;
        const us* cj = cwb_all + (size_t)(blk0 + j) * CC * CC;
        const float* dbj = db_all + (blk0 + j) * CC;
        const float* cbj = cb_all + (blk0 + j) * CC;

        // phase 1: dilated conv GEMM + relu -> gsm (packed 8B writes)
        #pragma unroll
        for (int ch = 0; ch < MAXCH; ++ch) {
            if (ch * 64 < Rn) {
                const int t = ch * 64 + rf * 16 + (lane & 15);
                const int tc = t > Rn - 1 ? Rn - 1 : t;
                bf16x8 af[4];
                af[0] = pack8(*(const f32x4*)(sm + sws(tc, c8)),
                              *(const f32x4*)(sm + sws(tc, c8 + 4)));
                af[1] = pack8(*(const f32x4*)(sm + sws(tc, 32 + c8)),
                              *(const f32x4*)(sm + sws(tc, 36 + c8)));
                af[2] = pack8(*(const f32x4*)(sm + sws(tc + d, c8)),
                              *(const f32x4*)(sm + sws(tc + d, c8 + 4)));
                af[3] = pack8(*(const f32x4*)(sm + sws(tc + d, 32 + c8)),
                              *(const f32x4*)(sm + sws(tc + d, 36 + c8)));
                #pragma unroll
                for (int n = 0; n < 2; ++n) {
                    const int orow = oh * 32 + n * 16 + (lane & 15);
                    const int o0   = oh * 32 + n * 16 + (lane >> 4) * 4;
                    f32x4 acc = *(const f32x4*)(dbj + o0);
                    const us* wr = wj + orow * 128 + c8;
                    acc = __builtin_amdgcn_mfma_f32_16x16x32_bf16(*(const bf16x8*)(wr),      af[0], acc, 0, 0, 0);
                    acc = __builtin_amdgcn_mfma_f32_16x16x32_bf16(*(const bf16x8*)(wr + 32), af[1], acc, 0, 0, 0);
                    acc = __builtin_amdgcn_mfma_f32_16x16x32_bf16(*(const bf16x8*)(wr + 64), af[2], acc, 0, 0, 0);
                    acc = __builtin_amdgcn_mfma_f32_16x16x32_bf16(*(const bf16x8*)(wr + 96), af[3], acc, 0, 0, 0);
                    #pragma unroll
                    for (int r = 0; r < 4; ++r) acc[r] = acc[r] > 0.f ? acc[r] : 0.f;
                    if (t < Rn) *(uint2*)(gsm + swh(t, o0)) = pk4(acc);
                }
            }
        }
        __syncthreads();

        // phase 2: prefetch residual source (fp32) + g-window store
        f32x4 oldv[MAXCH][2];
        #pragma unroll
        for (int ch = 0; ch < MAXCH; ++ch) {
            if (ch * 64 < Rn) {
                const int t = ch * 64 + rf * 16 + (lane & 15);
                const int tc = t > Rn - 1 ? Rn - 1 : t;
                #pragma unroll
                for (int n = 0; n < 2; ++n) {
                    const int o0 = oh * 32 + n * 16 + (lane >> 4) * 4;
                    oldv[ch][n] = *(const f32x4*)(sm + sws(tc + d, o0));
                }
            }
        }
        {
            const int wbase = Lj - SKIPN;
            us* gdst = g_all + ((size_t)(blk0 + j) * BB + b) * SKIPN * CC;
            const int ch8 = tid & 7;
            for (int grow = tid >> 3; grow < Rn; grow += 64) {
                const int gt = t0 + grow;
                if (gt < Lj && gt >= wbase)
                    *(bf16x8*)(gdst + ((size_t)(gt - wbase)) * CC + ch8 * 8) =
                        *(const bf16x8*)(gsm + swh(grow, ch8 * 8));
            }
        }
        __syncthreads();

        // phase 3: 1x1 GEMM + residual -> stream (packed 16B writes)
        #pragma unroll
        for (int ch = 0; ch < MAXCH; ++ch) {
            if (ch * 64 < Rn) {
                const int t = ch * 64 + rf * 16 + (lane & 15);
                const int tc = t > Rn - 1 ? Rn - 1 : t;
                bf16x8 g0 = *(const bf16x8*)(gsm + swh(tc, c8));
                bf16x8 g1 = *(const bf16x8*)(gsm + swh(tc, 32 + c8));
                #pragma unroll
                for (int n = 0; n < 2; ++n) {
                    const int orow = oh * 32 + n * 16 + (lane & 15);
                    const int o0   = oh * 32 + n * 16 + (lane >> 4) * 4;
                    f32x4 r = *(const f32x4*)(cbj + o0);
                    const us* wr = cj + orow * 64 + c8;
                    r = __builtin_amdgcn_mfma_f32_16x16x32_bf16(*(const bf16x8*)(wr),      g0, r, 0, 0, 0);
                    r = __builtin_amdgcn_mfma_f32_16x16x32_bf16(*(const bf16x8*)(wr + 32), g1, r, 0, 0, 0);
                    r += oldv[ch][n];
                    if (t < Rn) *(f32x4*)(sm + sws(t, o0)) = r;
                }
            }
        }
        __syncthreads();
        Rcur = Rn;
    }

    // final TOUT stream rows -> nxt
    float* dst = nxt + (size_t)b * LL0 * CC;
    for (int base = 0; base < TOUT; base += 32) {
        const int row = base + (tid >> 4);
        const int h4 = (tid & 15) * 4;
        const int gt = t0 + row;
        if (row < TOUT && gt < Lj)
            *(float4*)(dst + (size_t)gt * CC + h4) = *(const float4*)(sm + sws(row, h4));
    }
}

// ---- single-block kernel (256 threads), stream [b][t][c] ----
__global__ __launch_bounds__(256) void block_kernel(
    const float* __restrict__ cur, float* __restrict__ nxt,
    const us* __restrict__ wcat, const us* __restrict__ cwb,
    const float* __restrict__ db, const float* __restrict__ cb,
    us* __restrict__ g_out,
    int d, int Lin, int Lout, int ntiles,
    const us* __restrict__ g_all, const us* __restrict__ swb,
    const float* __restrict__ skip_b, float* __restrict__ out, int pb0)
{
    const int wg = blockIdx.x, chain = BB * ntiles;
    if (wg >= chain) { skip_body<4>(wg - chain, pb0, g_all, swb, skip_b, out); return; }

    __shared__ __align__(16) us xt[TTC * 128];
    __shared__ __align__(16) us gs[TTC * CC];
    __shared__ __align__(16) float x1f[TTC * CC];
    __shared__ __align__(16) float rs[TTC * CC];

    const int tid = threadIdx.x, lane = tid & 63, wv = tid >> 6;
    const int b = wg / ntiles, t0 = (wg % ntiles) * TTC;
    const float* src = cur + (size_t)b * LL0 * CC;

    #pragma unroll
    for (int p = 0; p < 2; ++p) {
        const int row = p * 16 + (tid >> 4);
        const int h4 = (tid & 15) * 4;
        int ta = t0 + row;     if (ta > Lin - 1) ta = Lin - 1;
        int tb = t0 + row + d; if (tb > Lin - 1) tb = Lin - 1;
        f32x4 v0 = *(const f32x4*)(src + (size_t)ta * CC + h4);
        f32x4 v1 = *(const f32x4*)(src + (size_t)tb * CC + h4);
        *(uint2*)(xt + swx(row, h4))      = pk4(v0);
        *(uint2*)(xt + swx(row, 64 + h4)) = pk4(v1);
        *(f32x4*)(x1f + sws(row, h4)) = v1;
    }
    __syncthreads();

    const int rf = wv >> 1, oh = wv & 1;
    const int t = rf * 16 + (lane & 15);
    const int c8 = (lane >> 4) * 8;

    // GEMM1 + relu -> gs
    bf16x8 af[4];
    #pragma unroll
    for (int ks = 0; ks < 4; ++ks)
        af[ks] = *(const bf16x8*)(xt + swx(t, ks * 32 + c8));
    #pragma unroll
    for (int n = 0; n < 2; ++n) {
        const int orow = oh * 32 + n * 16 + (lane & 15);
        const int o0   = oh * 32 + n * 16 + (lane >> 4) * 4;
        f32x4 acc = *(const f32x4*)(db + o0);
        const us* wr = wcat + orow * 128 + c8;
        acc = __builtin_amdgcn_mfma_f32_16x16x32_bf16(*(const bf16x8*)(wr),      af[0], acc, 0, 0, 0);
        acc = __builtin_amdgcn_mfma_f32_16x16x32_bf16(*(const bf16x8*)(wr + 32), af[1], acc, 0, 0, 0);
        acc = __builtin_amdgcn_mfma_f32_16x16x32_bf16(*(const bf16x8*)(wr + 64), af[2], acc, 0, 0, 0);
        acc = __builtin_amdgcn_mfma_f32_16x16x32_bf16(*(const bf16x8*)(wr + 96), af[3], acc, 0, 0, 0);
        #pragma unroll
        for (int r = 0; r < 4; ++r) acc[r] = acc[r] > 0.f ? acc[r] : 0.f;
        *(uint2*)(gs + swh(t, o0)) = pk4(acc);
    }
    __syncthreads();

    // GEMM2 + residual -> rs
    bf16x8 g0 = *(const bf16x8*)(gs + swh(t, c8));
    bf16x8 g1 = *(const bf16x8*)(gs + swh(t, 32 + c8));
    #pragma unroll
    for (int n = 0; n < 2; ++n) {
        const int orow = oh * 32 + n * 16 + (lane & 15);
        const int o0   = oh * 32 + n * 16 + (lane >> 4) * 4;
        f32x4 r = *(const f32x4*)(cb + o0);
        const us* wr = cwb + orow * 64 + c8;
        r = __builtin_amdgcn_mfma_f32_16x16x32_bf16(*(const bf16x8*)(wr),      g0, r, 0, 0, 0);
        r = __builtin_amdgcn_mfma_f32_16x16x32_bf16(*(const bf16x8*)(wr + 32), g1, r, 0, 0, 0);
        r += *(const f32x4*)(x1f + sws(t, o0));
        *(f32x4*)(rs + sws(t, o0)) = r;
    }
    __syncthreads();

    // coalesced out write + g window
    #pragma unroll
    for (int p = 0; p < 2; ++p) {
        const int row = p * 16 + (tid >> 4);
        const int h4 = (tid & 15) * 4;
        const int gt = t0 + row;
        if (gt < Lout)
            *(float4*)(nxt + (size_t)b * LL0 * CC + (size_t)gt * CC + h4) =
                *(const float4*)(rs + sws(row, h4));
    }
    {
        const int row = tid >> 3, ch8 = tid & 7;
        const int gt = t0 + row;
        const int wbase = Lout - SKIPN;
        if (gt >= wbase && gt < Lout)
            *(bf16x8*)(g_out + ((size_t)b * SKIPN + (gt - wbase)) * CC + ch8 * 8) =
                *(const bf16x8*)(gs + swh(row, ch8 * 8));
    }
}

__global__ __launch_bounds__(256) void skip_kernel(
    const us* __restrict__ g_all, const us* __restrict__ swb,
    const float* __restrict__ skip_b, float* __restrict__ out, int blk0)
{
    skip_body<4>(blockIdx.x, blk0, g_all, swb, skip_b, out);
}

extern "C" void kernel_launch(void* const* d_in, const int* in_sizes, int n_in,
                              void* d_out, int out_size, void* d_ws, size_t ws_size,
                              hipStream_t stream)
{
    const float* x      = (const float*)d_in[0];
    const float* dc_w   = (const float*)d_in[1];
    const float* dc_b   = (const float*)d_in[2];
    const float* conv_w = (const float*)d_in[3];
    const float* conv_b = (const float*)d_in[4];
    const float* skip_w = (const float*)d_in[5];
    const float* skip_b = (const float*)d_in[6];
    float* out = (float*)d_out;

    char* ws = (char*)d_ws;
    float* bufA = (float*)ws;  ws += (size_t)BB * LL0 * CC * 4;
    float* bufB = (float*)ws;  ws += (size_t)BB * LL0 * CC * 4;
    us* g_all = (us*)ws;       ws += (size_t)NBLK * BB * SKIPN * CC * 2;
    us* wcat  = (us*)ws;       ws += (size_t)NBLK * CC * 128 * 2;
    us* cwb   = (us*)ws;       ws += (size_t)NBLK * CC * CC * 2;
    us* swb   = (us*)ws;       ws += (size_t)NBLK * SCC * CC * 2;

    prep_kernel<<<1536, 256, 0, stream>>>(x, bufA, dc_w, conv_w, skip_w, wcat, cwb, swb);

    float* bufs[2] = {bufA, bufB};
    int Lc = LL0, blk = 0, q = 0, produced = 0, skipped = 0;
    for (int s = 0; s < 4; ++s) {
        {   // fused d = 1..32 (6 blocks), T=96, R0=159, LDS ~60KB
            const int Lout = Lc - 63;
            const int nt = (Lout + 95) / 96;
            int cap = produced - skipped; if (cap > 3) cap = 3;
            const int grid = BB * nt + cap * 128;   // skip_body<8>: 128 WGs/block
            fused_kernel<6, 1, 96, 160, 3><<<dim3(grid), 512, 0, stream>>>(
                bufs[q & 1], bufs[(q + 1) & 1], wcat, cwb, dc_b, conv_b,
                g_all, blk, Lc, nt, swb, skip_b, out, skipped);
            skipped += cap; produced += 6; blk += 6; Lc = Lout; ++q;
        }
        for (int dl = 6; dl < 10; ++dl) {   // d = 64..512 singles
            const int d = 1 << dl;
            const int Lout = Lc - d;
            const int nt = (Lout + TTC - 1) / TTC;
            int cap = produced - skipped; if (cap > 3) cap = 3;
            const int grid = BB * nt + cap * 256;   // skip_body<4>: 256 WGs/block
            block_kernel<<<dim3(grid), 256, 0, stream>>>(
                bufs[q & 1], bufs[(q + 1) & 1],
                wcat + (size_t)blk * CC * 128, cwb + (size_t)blk * CC * CC,
                dc_b + blk * CC, conv_b + blk * CC,
                g_all + (size_t)blk * BB * SKIPN * CC,
                d, Lc, Lout, nt, g_all, swb, skip_b, out, skipped);
            skipped += cap; produced += 1; blk += 1; Lc = Lout; ++q;
        }
    }
    const int rem = NBLK - skipped;
    if (rem > 0)
        skip_kernel<<<dim3(rem * 256), 256, 0, stream>>>(g_all, swb, skip_b, out, skipped);
}